// Round 4
// baseline (183.740 us; speedup 1.0000x reference)
//
#include <hip/hip_runtime.h>
#include <math.h>

#define NB   16      // batch
#define NTOK 4096    // N = 64*64
#define DIM  128
#define NE   8
#define HID  512
#define NOUT 128
#define GBLOCKS (NB * NTOK / 16)   // 4096 gate blocks (16 tokens/block)

// ws layout (all bytes read are written first each call):
//   s0      float[16*8]           @ 0     (512 B)
//   hitpart byte[4096]            @ 512   (4096 B)
//   gl      float[16][8][512]     @ 4608  (262144 B)
// total ~267 KB of ws.

// 16 lanes per token: coalesced float4 reads of x, butterfly-reduced gate
// logits, per-block hit bitmask (no global atomics), softmax score for
// expert 0 at n<8, and zero-fill of the output rows.
__global__ __launch_bounds__(256) void gate_kernel(
    const float4* __restrict__ x,        // (16,4096,128) f32 as float4
    const float* __restrict__ wg,        // (128,8)
    const float* __restrict__ bg,        // (8)
    float* __restrict__ s0,              // ws (16,8)
    unsigned char* __restrict__ hitpart, // ws (4096) one byte per block
    float4* __restrict__ out)            // (16,4096,128) f32
{
    __shared__ float4 lw4[NE][DIM / 4];  // wg transposed
    __shared__ float lbg[NE];
    __shared__ unsigned int lmask;

    int tid = threadIdx.x;
    {   // stage wg transposed (one float4 per thread)
        int e = tid >> 5, s = tid & 31, d0 = s * 4;
        float4 w;
        w.x = wg[(d0 + 0) * NE + e];
        w.y = wg[(d0 + 1) * NE + e];
        w.z = wg[(d0 + 2) * NE + e];
        w.w = wg[(d0 + 3) * NE + e];
        lw4[e][s] = w;
    }
    if (tid < NE) lbg[tid] = bg[tid];
    if (tid == 0) lmask = 0u;
    __syncthreads();

    int g   = blockIdx.x * 256 + tid;
    int tok = g >> 4;        // token id 0..65535
    int sub = g & 15;        // lane-within-token
    int b   = tok >> 12;
    int n   = tok & 4095;

    // this lane's 8 dims: [sub*4, +4) and [64+sub*4, +4)
    float4 xa = x[(size_t)tok * 32 + sub];
    float4 xb = x[(size_t)tok * 32 + sub + 16];

    float z[NE];
    #pragma unroll
    for (int e = 0; e < NE; e++) {
        float4 wa = lw4[e][sub];
        float4 wb = lw4[e][sub + 16];
        z[e] = xa.x * wa.x + xa.y * wa.y + xa.z * wa.z + xa.w * wa.w
             + xb.x * wb.x + xb.y * wb.y + xb.z * wb.z + xb.w * wb.w;
    }

    // butterfly sum across the 16 lanes of this token
    #pragma unroll
    for (int off = 1; off <= 8; off <<= 1) {
        #pragma unroll
        for (int e = 0; e < NE; e++) z[e] += __shfl_xor(z[e], off);
    }

    if (sub == 0) {
        float zf[NE];
        #pragma unroll
        for (int e = 0; e < NE; e++) zf[e] = z[e] + lbg[e];

        int am = 0;
        float mz = zf[0];
        #pragma unroll
        for (int e = 1; e < NE; e++) {
            if (zf[e] > mz) { mz = zf[e]; am = e; }
        }
        atomicOr(&lmask, 1u << am);   // LDS atomic, 16 per block

        if (n < 8) {                   // softmax score for expert 0
            float s = 0.f;
            #pragma unroll
            for (int e = 0; e < NE; e++) s += expf(zf[e] - mz);
            s0[b * NE + n] = expf(zf[0] - mz) / s;
        }
    }

    // zero-fill this token's output slice
    float4 zz = make_float4(0.f, 0.f, 0.f, 0.f);
    out[(size_t)tok * 32 + sub]      = zz;
    out[(size_t)tok * 32 + sub + 16] = zz;

    __syncthreads();
    if (tid == 0) hitpart[blockIdx.x] = (unsigned char)lmask;
}

// fc1 + dwconv + gelu for expert 0's 18 needed positions, split by channel.
// grid = 16 batches x 8 chunks of 64 channels = 128 blocks x 256 threads.
__global__ __launch_bounds__(256) void expert_a(
    const float* __restrict__ x,
    const float* __restrict__ W1,   // (8,128,512) -> expert 0 slice
    const float* __restrict__ B1,
    const float* __restrict__ Wd,   // (8,3,3,1,512)
    const float* __restrict__ Bd,
    float* __restrict__ gl_ws)      // ws (16,8,512)
{
    __shared__ float xs[18][DIM];   // 9216 B
    __shared__ float h1[18][64];    // 4608 B  (p = row*9+col)

    int b  = blockIdx.x >> 3;
    int c0 = (blockIdx.x & 7) * 64;
    int tid = threadIdx.x;

    // stage x at (row 0..1, col 0..8)
    for (int i = tid; i < 18 * DIM; i += 256) {
        int p = i >> 7, d = i & 127;
        int nn = (p / 9) * 64 + (p % 9);
        xs[p][d] = x[((size_t)b * NTOK + nn) * DIM + d];
    }
    __syncthreads();

    // fc1: wave pg handles positions {pg, pg+4, ...}, lane = channel
    {
        int pg = tid >> 6;       // 0..3 (wave-uniform)
        int cl = tid & 63;
        int c  = c0 + cl;
        float acc[5];
        #pragma unroll
        for (int k = 0; k < 5; k++) acc[k] = 0.f;
        for (int d = 0; d < DIM; d++) {
            float w = W1[(size_t)d * HID + c];
            #pragma unroll
            for (int k = 0; k < 5; k++) {
                int p = pg + 4 * k;
                if (p < 18) acc[k] += xs[p][d] * w;
            }
        }
        float b1 = B1[c];
        #pragma unroll
        for (int k = 0; k < 5; k++) {
            int p = pg + 4 * k;
            if (p < 18) h1[p][cl] = acc[k] + b1;
        }
    }
    __syncthreads();

    // depthwise 3x3 (SAME) at h=0, w=0..7, + bias + exact gelu
    #pragma unroll
    for (int r = 0; r < 2; r++) {
        int idx = tid + r * 256;
        int w  = idx >> 6;
        int cl = idx & 63;
        int c  = c0 + cl;
        float y = Bd[c];
        #pragma unroll
        for (int dw = 0; dw < 3; dw++) {
            int col = w - 1 + dw;
            if (col >= 0) {   // col <= 8 always in-range
                y += h1[col][cl]     * Wd[(size_t)(3 + dw) * HID + c]
                   + h1[9 + col][cl] * Wd[(size_t)(6 + dw) * HID + c];
            }
        }
        gl_ws[((size_t)b * 8 + w) * HID + c] =
            0.5f * y * (1.0f + erff(y * 0.70710678118654752f));
    }
}

// fc2 + gate scale for the 128 nonzero output rows.
// grid = 16 batches x 8 token positions = 128 blocks x 256 threads.
__global__ __launch_bounds__(256) void expert_b(
    const float* __restrict__ W2,   // (8,512,128) -> expert 0 slice
    const float* __restrict__ B2,
    const float* __restrict__ s0,
    const unsigned char* __restrict__ hitpart,
    const float* __restrict__ gl_ws,
    float* __restrict__ out)
{
    __shared__ float gls[HID];
    __shared__ float part[256];
    __shared__ unsigned int hm[NB];
    __shared__ float gate_s;

    int b = blockIdx.x >> 3;
    int w = blockIdx.x & 7;      // token position = gate index
    int tid = threadIdx.x;

    if (tid < NB) hm[tid] = 0u;
    __syncthreads();

    // OR-reduce hitpart: 4 threads x 16 uints per batch
    if (tid < 64) {
        int bb = tid >> 2, pt = tid & 3;
        const unsigned int* hp = (const unsigned int*)hitpart;
        unsigned int m = 0;
        #pragma unroll
        for (int j = 0; j < 16; j++) m |= hp[bb * 64 + pt * 16 + j];
        m |= m >> 16; m |= m >> 8; m &= 0xffu;
        atomicOr(&hm[bb], m);
    }
    for (int i = tid; i < HID; i += 256)
        gls[i] = gl_ws[((size_t)b * 8 + w) * HID + i];
    __syncthreads();

    if (tid == 0) {
        float denom = 1e-6f, mine = 0.f;
        for (int bb = 0; bb < NB; bb++) {
            float v = ((hm[bb] >> w) & 1u) ? s0[bb * NE + w] : 0.f;
            denom += v;
            if (bb == b) mine = v;
        }
        gate_s = 16.0f * mine / denom;
    }
    __syncthreads();

    // fc2: 2-way c-split, lane = output channel
    int o    = tid & 127;
    int half = tid >> 7;
    float a = 0.f;
    #pragma unroll 4
    for (int c = half * 256; c < half * 256 + 256; c++)
        a += gls[c] * W2[(size_t)c * NOUT + o];
    part[tid] = a;
    __syncthreads();
    if (tid < 128) {
        out[((size_t)b * NTOK + w) * NOUT + o] =
            (part[tid] + part[tid + 128] + B2[o]) * gate_s;
    }
}

extern "C" void kernel_launch(void* const* d_in, const int* in_sizes, int n_in,
                              void* d_out, int out_size, void* d_ws, size_t ws_size,
                              hipStream_t stream) {
    const float* x  = (const float*)d_in[0];
    // d_in[1] = H, d_in[2] = W (ints) — fixed 64x64, hard-coded
    const float* wg = (const float*)d_in[3];
    const float* bg = (const float*)d_in[4];
    const float* W1 = (const float*)d_in[5];
    const float* B1 = (const float*)d_in[6];
    const float* Wd = (const float*)d_in[7];
    const float* Bd = (const float*)d_in[8];
    const float* W2 = (const float*)d_in[9];
    const float* B2 = (const float*)d_in[10];

    float* s0              = (float*)d_ws;
    unsigned char* hitpart = (unsigned char*)d_ws + 512;
    float* gl_ws           = (float*)((char*)d_ws + 4608);

    gate_kernel<<<GBLOCKS, 256, 0, stream>>>(
        (const float4*)x, wg, bg, s0, hitpart, (float4*)d_out);
    expert_a<<<NB * 8, 256, 0, stream>>>(x, W1, B1, Wd, Bd, gl_ws);
    expert_b<<<NB * 8, 256, 0, stream>>>(W2, B2, s0, hitpart, gl_ws, (float*)d_out);
}

// Round 5
// 141.077 us; speedup vs baseline: 1.3024x; 1.3024x over previous
//
#include <hip/hip_runtime.h>
#include <math.h>

#define NB   16      // batch
#define NTOK 4096    // N = 64*64
#define DIM  128
#define NE   8
#define HID  512
#define NOUT 128
#define GBLOCKS (NB * NTOK / 16)   // 4096 gate blocks (16 tokens/block)

// ws layout (all bytes read are written first each call):
//   s0      float[16*8]           @ 0     (512 B)
//   hitpart byte[4096]            @ 512   (4096 B)
//   gl      float[16][8][512]     @ 4608  (262144 B)

// 16 lanes per token: coalesced float4 reads of x, butterfly-reduced gate
// logits, per-block hit bitmask (no global atomics), softmax score for
// expert 0 at n<8, and zero-fill of the output rows.
__global__ __launch_bounds__(256) void gate_kernel(
    const float4* __restrict__ x,        // (16,4096,128) f32 as float4
    const float* __restrict__ wg,        // (128,8)
    const float* __restrict__ bg,        // (8)
    float* __restrict__ s0,              // ws (16,8)
    unsigned char* __restrict__ hitpart, // ws (4096) one byte per block
    float4* __restrict__ out)            // (16,4096,128) f32
{
    __shared__ float4 lw4[NE][DIM / 4];  // wg transposed
    __shared__ float lbg[NE];
    __shared__ unsigned int lmask;

    int tid = threadIdx.x;
    {   // stage wg transposed (one float4 per thread)
        int e = tid >> 5, s = tid & 31, d0 = s * 4;
        float4 w;
        w.x = wg[(d0 + 0) * NE + e];
        w.y = wg[(d0 + 1) * NE + e];
        w.z = wg[(d0 + 2) * NE + e];
        w.w = wg[(d0 + 3) * NE + e];
        lw4[e][s] = w;
    }
    if (tid < NE) lbg[tid] = bg[tid];
    if (tid == 0) lmask = 0u;
    __syncthreads();

    int g   = blockIdx.x * 256 + tid;
    int tok = g >> 4;        // token id 0..65535
    int sub = g & 15;        // lane-within-token
    int b   = tok >> 12;
    int n   = tok & 4095;

    // this lane's 8 dims: [sub*4, +4) and [64+sub*4, +4)
    float4 xa = x[(size_t)tok * 32 + sub];
    float4 xb = x[(size_t)tok * 32 + sub + 16];

    float z[NE];
    #pragma unroll
    for (int e = 0; e < NE; e++) {
        float4 wa = lw4[e][sub];
        float4 wb = lw4[e][sub + 16];
        z[e] = xa.x * wa.x + xa.y * wa.y + xa.z * wa.z + xa.w * wa.w
             + xb.x * wb.x + xb.y * wb.y + xb.z * wb.z + xb.w * wb.w;
    }

    // butterfly sum across the 16 lanes of this token
    #pragma unroll
    for (int off = 1; off <= 8; off <<= 1) {
        #pragma unroll
        for (int e = 0; e < NE; e++) z[e] += __shfl_xor(z[e], off);
    }

    if (sub == 0) {
        float zf[NE];
        #pragma unroll
        for (int e = 0; e < NE; e++) zf[e] = z[e] + lbg[e];

        int am = 0;
        float mz = zf[0];
        #pragma unroll
        for (int e = 1; e < NE; e++) {
            if (zf[e] > mz) { mz = zf[e]; am = e; }
        }
        atomicOr(&lmask, 1u << am);   // LDS atomic, 16 per block

        if (n < 8) {                   // softmax score for expert 0
            float s = 0.f;
            #pragma unroll
            for (int e = 0; e < NE; e++) s += expf(zf[e] - mz);
            s0[b * NE + n] = expf(zf[0] - mz) / s;
        }
    }

    // zero-fill this token's output slice
    float4 zz = make_float4(0.f, 0.f, 0.f, 0.f);
    out[(size_t)tok * 32 + sub]      = zz;
    out[(size_t)tok * 32 + sub + 16] = zz;

    __syncthreads();
    if (tid == 0) hitpart[blockIdx.x] = (unsigned char)lmask;
}

// fc1 + dwconv + gelu for expert 0's 18 needed positions, split by channel.
// grid = 16 batches x 8 chunks of 64 channels = 128 blocks x 256 threads.
// W1 slice staged in LDS (8 independent float4 loads/thread) so the fc1
// d-loop runs from LDS instead of serializing 128 global round-trips.
__global__ __launch_bounds__(256) void expert_a(
    const float* __restrict__ x,
    const float* __restrict__ W1,   // (8,128,512) -> expert 0 slice
    const float* __restrict__ B1,
    const float* __restrict__ Wd,   // (8,3,3,1,512)
    const float* __restrict__ Bd,
    float* __restrict__ gl_ws)      // ws (16,8,512)
{
    __shared__ float xs[18][DIM];     //  9216 B
    __shared__ float4 w1s[DIM][16];   // 32768 B  (w1s[d][cq] = W1[d][c0+4cq..+4))
    __shared__ float h1[18][64];      //  4608 B

    int b  = blockIdx.x >> 3;
    int c0 = (blockIdx.x & 7) * 64;
    int tid = threadIdx.x;

    // stage W1 columns [c0, c0+64): 2048 float4, 8 per thread, all independent
    {
        const float4* W14 = (const float4*)W1;
        #pragma unroll
        for (int k = 0; k < 8; k++) {
            int q = tid + k * 256;
            int d = q >> 4, cq = q & 15;
            w1s[d][cq] = W14[d * (HID / 4) + (c0 >> 2) + cq];
        }
    }
    // stage x at (row 0..1, col 0..8): 576 float4, coalesced
    {
        const float4* x4 = (const float4*)x;
        #pragma unroll
        for (int k = 0; k < 3; k++) {
            int q = tid + k * 256;
            if (q < 18 * 32) {
                int p = q >> 5, dq = q & 31;
                int nn = (p / 9) * 64 + (p % 9);
                ((float4*)xs)[p * 32 + dq] = x4[((size_t)b * NTOK + nn) * 32 + dq];
            }
        }
    }
    __syncthreads();

    // fc1 from LDS: wave pg handles positions {pg, pg+4, ...}, lane = channel
    {
        int pg = tid >> 6;       // 0..3 (wave-uniform)
        int cl = tid & 63;
        const float* w1c = (const float*)w1s;   // [d][64]
        float acc[5];
        #pragma unroll
        for (int k = 0; k < 5; k++) acc[k] = 0.f;
        for (int d = 0; d < DIM; d++) {
            float w = w1c[d * 64 + cl];
            #pragma unroll
            for (int k = 0; k < 5; k++) {
                int p = pg + 4 * k;
                if (p < 18) acc[k] += xs[p][d] * w;
            }
        }
        float b1 = B1[c0 + cl];
        #pragma unroll
        for (int k = 0; k < 5; k++) {
            int p = pg + 4 * k;
            if (p < 18) h1[p][cl] = acc[k] + b1;
        }
    }
    __syncthreads();

    // depthwise 3x3 (SAME) at h=0, w=0..7, + bias + exact gelu
    #pragma unroll
    for (int r = 0; r < 2; r++) {
        int idx = tid + r * 256;
        int w  = idx >> 6;
        int cl = idx & 63;
        int c  = c0 + cl;
        float wd[6];
        #pragma unroll
        for (int j = 0; j < 6; j++) wd[j] = Wd[(size_t)(3 + j) * HID + c];
        float y = Bd[c];
        #pragma unroll
        for (int dw = 0; dw < 3; dw++) {
            int col = w - 1 + dw;
            if (col >= 0) {   // col <= 8 always in-range
                y += h1[col][cl] * wd[dw] + h1[9 + col][cl] * wd[3 + dw];
            }
        }
        gl_ws[((size_t)b * 8 + w) * HID + c] =
            0.5f * y * (1.0f + erff(y * 0.70710678118654752f));
    }
}

// fc2 + gate scale for the 128 nonzero output rows.
// grid = 16 batches x 8 token positions = 128 blocks x 256 threads.
// W2 loads register-batched 16-wide for MLP.
__global__ __launch_bounds__(256) void expert_b(
    const float* __restrict__ W2,   // (8,512,128) -> expert 0 slice
    const float* __restrict__ B2,
    const float* __restrict__ s0,
    const unsigned char* __restrict__ hitpart,
    const float* __restrict__ gl_ws,
    float* __restrict__ out)
{
    __shared__ float gls[HID];
    __shared__ float part[256];
    __shared__ unsigned int hm[NB];
    __shared__ float gate_s;

    int b = blockIdx.x >> 3;
    int w = blockIdx.x & 7;      // token position = gate index
    int tid = threadIdx.x;

    if (tid < NB) hm[tid] = 0u;
    __syncthreads();

    // OR-reduce hitpart: 4 threads x 16 uints per batch
    if (tid < 64) {
        int bb = tid >> 2, pt = tid & 3;
        const unsigned int* hp = (const unsigned int*)hitpart;
        unsigned int m = 0;
        #pragma unroll
        for (int j = 0; j < 16; j++) m |= hp[bb * 64 + pt * 16 + j];
        m |= m >> 16; m |= m >> 8; m &= 0xffu;
        atomicOr(&hm[bb], m);
    }
    if (tid < HID / 4) {
        ((float4*)gls)[tid] = ((const float4*)gl_ws)[((size_t)b * 8 + w) * (HID / 4) + tid];
    }
    __syncthreads();

    if (tid == 0) {
        float denom = 1e-6f, mine = 0.f;
        for (int bb = 0; bb < NB; bb++) {
            float v = ((hm[bb] >> w) & 1u) ? s0[bb * NE + w] : 0.f;
            denom += v;
            if (bb == b) mine = v;
        }
        gate_s = 16.0f * mine / denom;
    }

    // fc2: 2-way c-split, lane = output channel, 16 loads in flight
    int o    = tid & 127;
    int half = tid >> 7;
    const float* wp = W2 + (size_t)(half * 256) * NOUT + o;
    const float* gp = gls + half * 256;
    float a = 0.f;
    for (int cb = 0; cb < 256; cb += 16) {
        float wv[16];
        #pragma unroll
        for (int k = 0; k < 16; k++) wv[k] = wp[(size_t)(cb + k) * NOUT];
        #pragma unroll
        for (int k = 0; k < 16; k++) a += gp[cb + k] * wv[k];
    }
    part[tid] = a;
    __syncthreads();
    if (tid < 128) {
        out[((size_t)b * NTOK + w) * NOUT + o] =
            (part[tid] + part[tid + 128] + B2[o]) * gate_s;
    }
}

extern "C" void kernel_launch(void* const* d_in, const int* in_sizes, int n_in,
                              void* d_out, int out_size, void* d_ws, size_t ws_size,
                              hipStream_t stream) {
    const float* x  = (const float*)d_in[0];
    // d_in[1] = H, d_in[2] = W (ints) — fixed 64x64, hard-coded
    const float* wg = (const float*)d_in[3];
    const float* bg = (const float*)d_in[4];
    const float* W1 = (const float*)d_in[5];
    const float* B1 = (const float*)d_in[6];
    const float* Wd = (const float*)d_in[7];
    const float* Bd = (const float*)d_in[8];
    const float* W2 = (const float*)d_in[9];
    const float* B2 = (const float*)d_in[10];

    float* s0              = (float*)d_ws;
    unsigned char* hitpart = (unsigned char*)d_ws + 512;
    float* gl_ws           = (float*)((char*)d_ws + 4608);

    gate_kernel<<<GBLOCKS, 256, 0, stream>>>(
        (const float4*)x, wg, bg, s0, hitpart, (float4*)d_out);
    expert_a<<<NB * 8, 256, 0, stream>>>(x, W1, B1, Wd, Bd, gl_ws);
    expert_b<<<NB * 8, 256, 0, stream>>>(W2, B2, s0, hitpart, gl_ws, (float*)d_out);
}

// Round 6
// 138.278 us; speedup vs baseline: 1.3288x; 1.0202x over previous
//
#include <hip/hip_runtime.h>
#include <math.h>

#define NB   16      // batch
#define NTOK 4096    // N = 64*64
#define DIM  128
#define NE   8
#define HID  512
#define NOUT 128
#define GBLOCKS (NB * NTOK * 8 / 256)   // 2048 gate blocks (32 tokens/block)

// ws layout (all bytes read are written first each call):
//   s0      float[16*8]           @ 0     (512 B)
//   hitpart byte[2048]            @ 512   (2048 B)
//   gl      float[16][8][512]     @ 4608  (262144 B)

// 8 lanes per token (16 dims each): coalesced float4 reads of x, 3-step
// butterfly (xor1/xor2 = DPP, xor4 = 1 LDS step), per-block hit bitmask,
// softmax score for expert 0 at n<8, zero-fill of output rows issued first.
__global__ __launch_bounds__(256) void gate_kernel(
    const float4* __restrict__ x,        // (16,4096,128) f32 as float4
    const float* __restrict__ wg,        // (128,8)
    const float* __restrict__ bg,        // (8)
    float* __restrict__ s0,              // ws (16,8)
    unsigned char* __restrict__ hitpart, // ws (2048) one byte per block
    float4* __restrict__ out)            // (16,4096,128) f32
{
    __shared__ float4 lw4[NE][DIM / 4];  // wg transposed: lw4[e][s] = wg[4s..4s+3, e]
    __shared__ float lbg[NE];
    __shared__ unsigned int lmask;

    int tid = threadIdx.x;
    {   // stage wg transposed (one float4 per thread)
        int e = tid >> 5, s = tid & 31, d0 = s * 4;
        float4 w;
        w.x = wg[(d0 + 0) * NE + e];
        w.y = wg[(d0 + 1) * NE + e];
        w.z = wg[(d0 + 2) * NE + e];
        w.w = wg[(d0 + 3) * NE + e];
        lw4[e][s] = w;
    }
    if (tid < NE) lbg[tid] = bg[tid];
    if (tid == 0) lmask = 0u;
    __syncthreads();

    int g   = blockIdx.x * 256 + tid;
    int tok = g >> 3;        // token id 0..65535
    int sub = g & 7;         // lane-within-token
    int b   = tok >> 12;
    int n   = tok & 4095;

    size_t base = (size_t)tok * 32 + sub;

    // zero-fill first: independent stores overlap the load latency
    float4 zz = make_float4(0.f, 0.f, 0.f, 0.f);
    out[base]      = zz;
    out[base + 8]  = zz;
    out[base + 16] = zz;
    out[base + 24] = zz;

    // this lane's 16 dims: float4s {sub, sub+8, sub+16, sub+24}
    float4 xv[4];
    xv[0] = x[base];
    xv[1] = x[base + 8];
    xv[2] = x[base + 16];
    xv[3] = x[base + 24];

    float z[NE];
    #pragma unroll
    for (int e = 0; e < NE; e++) {
        float a = 0.f;
        #pragma unroll
        for (int k = 0; k < 4; k++) {
            float4 w = lw4[e][sub + 8 * k];
            a += xv[k].x * w.x + xv[k].y * w.y + xv[k].z * w.z + xv[k].w * w.w;
        }
        z[e] = a;
    }

    // butterfly sum across the 8 lanes of this token (xor 1,2,4)
    #pragma unroll
    for (int off = 1; off <= 4; off <<= 1) {
        #pragma unroll
        for (int e = 0; e < NE; e++) z[e] += __shfl_xor(z[e], off);
    }

    if (sub == 0) {
        float zf[NE];
        #pragma unroll
        for (int e = 0; e < NE; e++) zf[e] = z[e] + lbg[e];

        int am = 0;
        float mz = zf[0];
        #pragma unroll
        for (int e = 1; e < NE; e++) {
            if (zf[e] > mz) { mz = zf[e]; am = e; }
        }
        atomicOr(&lmask, 1u << am);   // LDS atomic, 32 per block

        if (n < 8) {                   // softmax score for expert 0
            float s = 0.f;
            #pragma unroll
            for (int e = 0; e < NE; e++) s += expf(zf[e] - mz);
            s0[b * NE + n] = expf(zf[0] - mz) / s;
        }
    }

    __syncthreads();
    if (tid == 0) hitpart[blockIdx.x] = (unsigned char)lmask;
}

// fc1 + dwconv + gelu for expert 0's 18 needed positions, split by channel.
// grid = 16 batches x 8 chunks of 64 channels = 128 blocks x 256 threads.
// W1 slice staged in LDS (8 independent float4 loads/thread).
__global__ __launch_bounds__(256) void expert_a(
    const float* __restrict__ x,
    const float* __restrict__ W1,   // (8,128,512) -> expert 0 slice
    const float* __restrict__ B1,
    const float* __restrict__ Wd,   // (8,3,3,1,512)
    const float* __restrict__ Bd,
    float* __restrict__ gl_ws)      // ws (16,8,512)
{
    __shared__ float xs[18][DIM];     //  9216 B
    __shared__ float4 w1s[DIM][16];   // 32768 B
    __shared__ float h1[18][64];      //  4608 B

    int b  = blockIdx.x >> 3;
    int c0 = (blockIdx.x & 7) * 64;
    int tid = threadIdx.x;

    // stage W1 columns [c0, c0+64): 2048 float4, 8 per thread, independent
    {
        const float4* W14 = (const float4*)W1;
        #pragma unroll
        for (int k = 0; k < 8; k++) {
            int q = tid + k * 256;
            int d = q >> 4, cq = q & 15;
            w1s[d][cq] = W14[d * (HID / 4) + (c0 >> 2) + cq];
        }
    }
    // stage x at (row 0..1, col 0..8): 576 float4, coalesced
    {
        const float4* x4 = (const float4*)x;
        #pragma unroll
        for (int k = 0; k < 3; k++) {
            int q = tid + k * 256;
            if (q < 18 * 32) {
                int p = q >> 5, dq = q & 31;
                int nn = (p / 9) * 64 + (p % 9);
                ((float4*)xs)[p * 32 + dq] = x4[((size_t)b * NTOK + nn) * 32 + dq];
            }
        }
    }
    __syncthreads();

    // fc1 from LDS: wave pg handles positions {pg, pg+4, ...}, lane = channel
    {
        int pg = tid >> 6;       // 0..3 (wave-uniform)
        int cl = tid & 63;
        const float* w1c = (const float*)w1s;   // [d][64]
        float acc[5];
        #pragma unroll
        for (int k = 0; k < 5; k++) acc[k] = 0.f;
        for (int d = 0; d < DIM; d++) {
            float w = w1c[d * 64 + cl];
            #pragma unroll
            for (int k = 0; k < 5; k++) {
                int p = pg + 4 * k;
                if (p < 18) acc[k] += xs[p][d] * w;
            }
        }
        float b1 = B1[c0 + cl];
        #pragma unroll
        for (int k = 0; k < 5; k++) {
            int p = pg + 4 * k;
            if (p < 18) h1[p][cl] = acc[k] + b1;
        }
    }
    __syncthreads();

    // depthwise 3x3 (SAME) at h=0, w=0..7, + bias + exact gelu
    #pragma unroll
    for (int r = 0; r < 2; r++) {
        int idx = tid + r * 256;
        int w  = idx >> 6;
        int cl = idx & 63;
        int c  = c0 + cl;
        float wd[6];
        #pragma unroll
        for (int j = 0; j < 6; j++) wd[j] = Wd[(size_t)(3 + j) * HID + c];
        float y = Bd[c];
        #pragma unroll
        for (int dw = 0; dw < 3; dw++) {
            int col = w - 1 + dw;
            if (col >= 0) {   // col <= 8 always in-range
                y += h1[col][cl] * wd[dw] + h1[9 + col][cl] * wd[3 + dw];
            }
        }
        gl_ws[((size_t)b * 8 + w) * HID + c] =
            0.5f * y * (1.0f + erff(y * 0.70710678118654752f));
    }
}

// fc2 + gate scale for the 128 nonzero output rows.
// grid = 16 batches x 8 token positions = 128 blocks x 256 threads.
__global__ __launch_bounds__(256) void expert_b(
    const float* __restrict__ W2,   // (8,512,128) -> expert 0 slice
    const float* __restrict__ B2,
    const float* __restrict__ s0,
    const unsigned char* __restrict__ hitpart,
    const float* __restrict__ gl_ws,
    float* __restrict__ out)
{
    __shared__ float gls[HID];
    __shared__ float part[256];
    __shared__ unsigned int hm[NB];
    __shared__ float gate_s;

    int b = blockIdx.x >> 3;
    int w = blockIdx.x & 7;      // token position = gate index
    int tid = threadIdx.x;

    if (tid < NB) hm[tid] = 0u;
    __syncthreads();

    // OR-reduce hitpart (2048 bytes = 512 uints): 4 threads x 8 uints per batch
    if (tid < 64) {
        int bb = tid >> 2, pt = tid & 3;
        const unsigned int* hp = (const unsigned int*)hitpart;
        unsigned int m = 0;
        #pragma unroll
        for (int j = 0; j < 8; j++) m |= hp[bb * 32 + pt * 8 + j];
        m |= m >> 16; m |= m >> 8; m &= 0xffu;
        atomicOr(&hm[bb], m);
    }
    if (tid < HID / 4) {
        ((float4*)gls)[tid] = ((const float4*)gl_ws)[((size_t)b * 8 + w) * (HID / 4) + tid];
    }
    __syncthreads();

    if (tid == 0) {
        float denom = 1e-6f, mine = 0.f;
        for (int bb = 0; bb < NB; bb++) {
            float v = ((hm[bb] >> w) & 1u) ? s0[bb * NE + w] : 0.f;
            denom += v;
            if (bb == b) mine = v;
        }
        gate_s = 16.0f * mine / denom;
    }

    // fc2: 2-way c-split, lane = output channel, 16 loads in flight
    int o    = tid & 127;
    int half = tid >> 7;
    const float* wp = W2 + (size_t)(half * 256) * NOUT + o;
    const float* gp = gls + half * 256;
    float a = 0.f;
    for (int cb = 0; cb < 256; cb += 16) {
        float wv[16];
        #pragma unroll
        for (int k = 0; k < 16; k++) wv[k] = wp[(size_t)(cb + k) * NOUT];
        #pragma unroll
        for (int k = 0; k < 16; k++) a += gp[cb + k] * wv[k];
    }
    part[tid] = a;
    __syncthreads();
    if (tid < 128) {
        out[((size_t)b * NTOK + w) * NOUT + o] =
            (part[tid] + part[tid + 128] + B2[o]) * gate_s;
    }
}

extern "C" void kernel_launch(void* const* d_in, const int* in_sizes, int n_in,
                              void* d_out, int out_size, void* d_ws, size_t ws_size,
                              hipStream_t stream) {
    const float* x  = (const float*)d_in[0];
    // d_in[1] = H, d_in[2] = W (ints) — fixed 64x64, hard-coded
    const float* wg = (const float*)d_in[3];
    const float* bg = (const float*)d_in[4];
    const float* W1 = (const float*)d_in[5];
    const float* B1 = (const float*)d_in[6];
    const float* Wd = (const float*)d_in[7];
    const float* Bd = (const float*)d_in[8];
    const float* W2 = (const float*)d_in[9];
    const float* B2 = (const float*)d_in[10];

    float* s0              = (float*)d_ws;
    unsigned char* hitpart = (unsigned char*)d_ws + 512;
    float* gl_ws           = (float*)((char*)d_ws + 4608);

    gate_kernel<<<GBLOCKS, 256, 0, stream>>>(
        (const float4*)x, wg, bg, s0, hitpart, (float4*)d_out);
    expert_a<<<NB * 8, 256, 0, stream>>>(x, W1, B1, Wd, Bd, gl_ws);
    expert_b<<<NB * 8, 256, 0, stream>>>(W2, B2, s0, hitpart, gl_ws, (float*)d_out);
}

// Round 7
// 134.518 us; speedup vs baseline: 1.3659x; 1.0280x over previous
//
#include <hip/hip_runtime.h>
#include <math.h>

#define NB   16      // batch
#define NTOK 4096    // N = 64*64
#define DIM  128
#define NE   8
#define HID  512
#define NOUT 128
#define GBLOCKS (NB * NTOK * 8 / 256)   // 2048 gate blocks (32 tokens/block)

// ws layout (all bytes read are written first each call):
//   s0      float[16*8]   @ 0    (512 B)
//   hitpart byte[2048]    @ 512  (2048 B)

// 8 lanes per token (16 dims each): coalesced float4 reads of x, 3-step
// butterfly, per-block hit bitmask, softmax score for expert 0 at n<8,
// zero-fill of output rows issued first (overlaps load latency).
__global__ __launch_bounds__(256) void gate_kernel(
    const float4* __restrict__ x,        // (16,4096,128) f32 as float4
    const float* __restrict__ wg,        // (128,8)
    const float* __restrict__ bg,        // (8)
    float* __restrict__ s0,              // ws (16,8)
    unsigned char* __restrict__ hitpart, // ws (2048) one byte per block
    float4* __restrict__ out)            // (16,4096,128) f32
{
    __shared__ float4 lw4[NE][DIM / 4];  // wg transposed
    __shared__ float lbg[NE];
    __shared__ unsigned int lmask;

    int tid = threadIdx.x;
    {   // stage wg transposed (one float4 per thread)
        int e = tid >> 5, s = tid & 31, d0 = s * 4;
        float4 w;
        w.x = wg[(d0 + 0) * NE + e];
        w.y = wg[(d0 + 1) * NE + e];
        w.z = wg[(d0 + 2) * NE + e];
        w.w = wg[(d0 + 3) * NE + e];
        lw4[e][s] = w;
    }
    if (tid < NE) lbg[tid] = bg[tid];
    if (tid == 0) lmask = 0u;
    __syncthreads();

    int g   = blockIdx.x * 256 + tid;
    int tok = g >> 3;        // token id 0..65535
    int sub = g & 7;         // lane-within-token
    int b   = tok >> 12;
    int n   = tok & 4095;

    size_t base = (size_t)tok * 32 + sub;

    // zero-fill first: independent stores overlap the load latency
    float4 zz = make_float4(0.f, 0.f, 0.f, 0.f);
    out[base]      = zz;
    out[base + 8]  = zz;
    out[base + 16] = zz;
    out[base + 24] = zz;

    // this lane's 16 dims: float4s {sub, sub+8, sub+16, sub+24}
    float4 xv[4];
    xv[0] = x[base];
    xv[1] = x[base + 8];
    xv[2] = x[base + 16];
    xv[3] = x[base + 24];

    float z[NE];
    #pragma unroll
    for (int e = 0; e < NE; e++) {
        float a = 0.f;
        #pragma unroll
        for (int k = 0; k < 4; k++) {
            float4 w = lw4[e][sub + 8 * k];
            a += xv[k].x * w.x + xv[k].y * w.y + xv[k].z * w.z + xv[k].w * w.w;
        }
        z[e] = a;
    }

    // butterfly sum across the 8 lanes of this token (xor 1,2,4)
    #pragma unroll
    for (int off = 1; off <= 4; off <<= 1) {
        #pragma unroll
        for (int e = 0; e < NE; e++) z[e] += __shfl_xor(z[e], off);
    }

    if (sub == 0) {
        float zf[NE];
        #pragma unroll
        for (int e = 0; e < NE; e++) zf[e] = z[e] + lbg[e];

        int am = 0;
        float mz = zf[0];
        #pragma unroll
        for (int e = 1; e < NE; e++) {
            if (zf[e] > mz) { mz = zf[e]; am = e; }
        }
        atomicOr(&lmask, 1u << am);   // LDS atomic, 32 per block

        if (n < 8) {                   // softmax score for expert 0
            float s = 0.f;
            #pragma unroll
            for (int e = 0; e < NE; e++) s += expf(zf[e] - mz);
            s0[b * NE + n] = expf(zf[0] - mz) / s;
        }
    }

    __syncthreads();
    if (tid == 0) hitpart[blockIdx.x] = (unsigned char)lmask;
}

// Fused expert-0 MixFFN + gate scale for the 128 nonzero output rows.
// grid = 16 batches x 8 token positions (w), 256 threads.
// Thread owns channels (c=tid, c+256). x values are block-uniform ->
// scalar (SGPR) loads; fc1 accumulators and the depthwise conv live
// entirely in registers; only the 512-float gelu vector goes via LDS.
__global__ __launch_bounds__(256) void expert_kernel(
    const float* __restrict__ x,
    const float* __restrict__ W1,   // (8,128,512) -> expert 0 slice
    const float* __restrict__ B1,   // (8,512)
    const float* __restrict__ Wd,   // (8,3,3,1,512)
    const float* __restrict__ Bd,   // (8,512)
    const float* __restrict__ W2,   // (8,512,128) -> expert 0 slice
    const float* __restrict__ B2,   // (8,128)
    const float* __restrict__ s0,
    const unsigned char* __restrict__ hitpart,
    float* __restrict__ out)
{
    __shared__ float gls[HID];
    __shared__ float red[256];
    __shared__ unsigned int hm[NB];
    __shared__ float gate_s;

    int b = blockIdx.x >> 3;
    int w = blockIdx.x & 7;      // token position = gate index
    int tid = threadIdx.x;

    if (tid < NB) hm[tid] = 0u;
    __syncthreads();

    // OR-reduce hitpart (2048 bytes = 512 uints): 4 threads x 8 uints/batch
    if (tid < 64) {
        int bb = tid >> 2, pt = tid & 3;
        const unsigned int* hp = (const unsigned int*)hitpart;
        unsigned int m = 0;
        #pragma unroll
        for (int j = 0; j < 8; j++) m |= hp[bb * 32 + pt * 8 + j];
        m |= m >> 16; m |= m >> 8; m &= 0xffu;
        atomicOr(&hm[bb], m);
    }

    // fc1 for (rows 0..1) x (cols w-1..w+1), channels c=tid and c+256.
    // x addresses are block-uniform -> compiler scalarizes to s_load.
    float acc0[6], acc1[6];      // [row*3+ci]
    #pragma unroll
    for (int p = 0; p < 6; p++) { acc0[p] = 0.f; acc1[p] = 0.f; }

    const float* xb = x + (size_t)b * NTOK * DIM;

    #pragma unroll 2
    for (int d0 = 0; d0 < DIM; d0 += 4) {
        float wa[4], wb[4];
        #pragma unroll
        for (int j = 0; j < 4; j++) {
            wa[j] = W1[(size_t)(d0 + j) * HID + tid];
            wb[j] = W1[(size_t)(d0 + j) * HID + tid + 256];
        }
        #pragma unroll
        for (int row = 0; row < 2; row++) {
            #pragma unroll
            for (int ci = 0; ci < 3; ci++) {
                int col = w - 1 + ci;        // block-uniform branch
                if (col < 0) continue;       // col <= 8 always in-range
                const float* xp = xb + (size_t)(row * 64 + col) * DIM + d0;
                float x0 = xp[0], x1 = xp[1], x2 = xp[2], x3 = xp[3];
                int p = row * 3 + ci;
                acc0[p] += x0 * wa[0] + x1 * wa[1] + x2 * wa[2] + x3 * wa[3];
                acc1[p] += x0 * wb[0] + x1 * wb[1] + x2 * wb[2] + x3 * wb[3];
            }
        }
    }

    // + B1, depthwise 3x3 (kernel rows kh=1,2 hit input rows 0,1), + Bd, gelu
    {
        float b1a = B1[tid], b1b = B1[tid + 256];
        float ya = Bd[tid], yb = Bd[tid + 256];
        #pragma unroll
        for (int ci = 0; ci < 3; ci++) {
            int col = w - 1 + ci;
            if (col < 0) continue;           // padded -> contributes 0
            float w1a = Wd[(size_t)(3 + ci) * HID + tid];
            float w2a = Wd[(size_t)(6 + ci) * HID + tid];
            float w1b = Wd[(size_t)(3 + ci) * HID + tid + 256];
            float w2b = Wd[(size_t)(6 + ci) * HID + tid + 256];
            ya += (acc0[ci] + b1a) * w1a + (acc0[3 + ci] + b1a) * w2a;
            yb += (acc1[ci] + b1b) * w1b + (acc1[3 + ci] + b1b) * w2b;
        }
        gls[tid]       = 0.5f * ya * (1.0f + erff(ya * 0.70710678118654752f));
        gls[tid + 256] = 0.5f * yb * (1.0f + erff(yb * 0.70710678118654752f));
    }
    __syncthreads();   // gls complete + hm complete

    if (tid == 0) {
        float denom = 1e-6f, mine = 0.f;
        for (int bb = 0; bb < NB; bb++) {
            float v = ((hm[bb] >> w) & 1u) ? s0[bb * NE + w] : 0.f;
            denom += v;
            if (bb == b) mine = v;
        }
        gate_s = 16.0f * mine / denom;
    }

    // fc2: 2-way c-split, lane = output channel, 16 W2 loads in flight
    int o    = tid & 127;
    int half = tid >> 7;
    const float* wp = W2 + (size_t)(half * 256) * NOUT + o;
    const float4* gp = (const float4*)&gls[half * 256];
    float a = 0.f;
    for (int cb = 0; cb < 256; cb += 16) {
        float wv[16];
        #pragma unroll
        for (int k = 0; k < 16; k++) wv[k] = wp[(size_t)(cb + k) * NOUT];
        float4 g0 = gp[(cb >> 2) + 0];
        float4 g1 = gp[(cb >> 2) + 1];
        float4 g2 = gp[(cb >> 2) + 2];
        float4 g3 = gp[(cb >> 2) + 3];
        a += g0.x * wv[0]  + g0.y * wv[1]  + g0.z * wv[2]  + g0.w * wv[3]
           + g1.x * wv[4]  + g1.y * wv[5]  + g1.z * wv[6]  + g1.w * wv[7]
           + g2.x * wv[8]  + g2.y * wv[9]  + g2.z * wv[10] + g2.w * wv[11]
           + g3.x * wv[12] + g3.y * wv[13] + g3.z * wv[14] + g3.w * wv[15];
    }
    red[tid] = a;
    __syncthreads();
    if (tid < 128) {
        out[((size_t)b * NTOK + w) * NOUT + o] =
            (red[tid] + red[tid + 128] + B2[o]) * gate_s;
    }
}

extern "C" void kernel_launch(void* const* d_in, const int* in_sizes, int n_in,
                              void* d_out, int out_size, void* d_ws, size_t ws_size,
                              hipStream_t stream) {
    const float* x  = (const float*)d_in[0];
    // d_in[1] = H, d_in[2] = W (ints) — fixed 64x64, hard-coded
    const float* wg = (const float*)d_in[3];
    const float* bg = (const float*)d_in[4];
    const float* W1 = (const float*)d_in[5];
    const float* B1 = (const float*)d_in[6];
    const float* Wd = (const float*)d_in[7];
    const float* Bd = (const float*)d_in[8];
    const float* W2 = (const float*)d_in[9];
    const float* B2 = (const float*)d_in[10];

    float* s0              = (float*)d_ws;
    unsigned char* hitpart = (unsigned char*)d_ws + 512;

    gate_kernel<<<GBLOCKS, 256, 0, stream>>>(
        (const float4*)x, wg, bg, s0, hitpart, (float4*)d_out);
    expert_kernel<<<NB * 8, 256, 0, stream>>>(
        x, W1, B1, Wd, Bd, W2, B2, s0, hitpart, (float*)d_out);
}

// Round 8
// 134.428 us; speedup vs baseline: 1.3668x; 1.0007x over previous
//
#include <hip/hip_runtime.h>
#include <math.h>

#define NB   16      // batch
#define NTOK 4096    // N = 64*64
#define DIM  128
#define NE   8
#define HID  512
#define NOUT 128
#define GBLK 512     // gate blocks: each covers 128 contiguous tokens (1 batch = 32 blocks)

// ws layout (all bytes read are written first each call):
//   s0      float[16*8]   @ 0    (512 B)
//   hitpart byte[512]     @ 512  (512 B)

// 8 lanes per token, grid-stride x4 tokens per lane. Gate weights are hoisted
// from LDS into VGPRs once (32 ds_read_b128/wave) and reused across the 4
// token-groups, so the steady-state loop touches only the memory pipe:
// 4 zero-stores + 4 x-loads + 32 VALU-fma + 3-step butterfly per group.
__global__ __launch_bounds__(256) void gate_kernel(
    const float4* __restrict__ x,        // (16,4096,128) f32 as float4
    const float* __restrict__ wg,        // (128,8)
    const float* __restrict__ bg,        // (8)
    float* __restrict__ s0,              // ws (16,8)
    unsigned char* __restrict__ hitpart, // ws (512) one byte per block
    float4* __restrict__ out)            // (16,4096,128) f32
{
    __shared__ float4 lw4[NE][DIM / 4];  // wg transposed
    __shared__ float lbg[NE];
    __shared__ unsigned int lmask;

    int tid = threadIdx.x;
    {   // stage wg transposed (one float4 per thread)
        int e = tid >> 5, s = tid & 31, d0 = s * 4;
        float4 w;
        w.x = wg[(d0 + 0) * NE + e];
        w.y = wg[(d0 + 1) * NE + e];
        w.z = wg[(d0 + 2) * NE + e];
        w.w = wg[(d0 + 3) * NE + e];
        lw4[e][s] = w;
    }
    if (tid < NE) lbg[tid] = bg[tid];
    if (tid == 0) lmask = 0u;
    __syncthreads();

    int sub  = tid & 7;       // lane-within-token
    int tgrp = tid >> 3;      // token-within-chunk (0..31)

    // hoist this lane's weight slice into VGPRs (reused for all 4 groups)
    float4 wv[NE][4];
    #pragma unroll
    for (int e = 0; e < NE; e++)
        #pragma unroll
        for (int k = 0; k < 4; k++) wv[e][k] = lw4[e][sub + 8 * k];

    #pragma unroll 2
    for (int it = 0; it < 4; it++) {
        int tok = (blockIdx.x << 7) + (it << 5) + tgrp;   // 0..65535
        int b   = tok >> 12;
        int n   = tok & 4095;
        size_t base = (size_t)tok * 32 + sub;

        // zero-fill first: independent stores overlap the load latency
        float4 zz = make_float4(0.f, 0.f, 0.f, 0.f);
        out[base]      = zz;
        out[base + 8]  = zz;
        out[base + 16] = zz;
        out[base + 24] = zz;

        float4 xv0 = x[base];
        float4 xv1 = x[base + 8];
        float4 xv2 = x[base + 16];
        float4 xv3 = x[base + 24];

        float z[NE];
        #pragma unroll
        for (int e = 0; e < NE; e++) {
            z[e] = xv0.x * wv[e][0].x + xv0.y * wv[e][0].y
                 + xv0.z * wv[e][0].z + xv0.w * wv[e][0].w
                 + xv1.x * wv[e][1].x + xv1.y * wv[e][1].y
                 + xv1.z * wv[e][1].z + xv1.w * wv[e][1].w
                 + xv2.x * wv[e][2].x + xv2.y * wv[e][2].y
                 + xv2.z * wv[e][2].z + xv2.w * wv[e][2].w
                 + xv3.x * wv[e][3].x + xv3.y * wv[e][3].y
                 + xv3.z * wv[e][3].z + xv3.w * wv[e][3].w;
        }

        // butterfly sum across the 8 lanes of this token (xor 1,2,4)
        #pragma unroll
        for (int off = 1; off <= 4; off <<= 1) {
            #pragma unroll
            for (int e = 0; e < NE; e++) z[e] += __shfl_xor(z[e], off);
        }

        if (sub == 0) {
            float zf[NE];
            #pragma unroll
            for (int e = 0; e < NE; e++) zf[e] = z[e] + lbg[e];

            int am = 0;
            float mz = zf[0];
            #pragma unroll
            for (int e = 1; e < NE; e++) {
                if (zf[e] > mz) { mz = zf[e]; am = e; }
            }
            atomicOr(&lmask, 1u << am);   // LDS atomic

            if (n < 8) {                   // softmax score for expert 0
                float s = 0.f;
                #pragma unroll
                for (int e = 0; e < NE; e++) s += expf(zf[e] - mz);
                s0[b * NE + n] = expf(zf[0] - mz) / s;
            }
        }
    }

    __syncthreads();
    if (tid == 0) hitpart[blockIdx.x] = (unsigned char)lmask;
}

// Fused expert-0 MixFFN + gate scale for the 128 nonzero output rows.
// grid = 16 batches x 8 token positions (w), 256 threads.
// Thread owns channels (c=tid, c+256). x values are block-uniform ->
// scalar (SGPR) loads; fc1 accumulators and the depthwise conv live
// entirely in registers; only the 512-float gelu vector goes via LDS.
__global__ __launch_bounds__(256) void expert_kernel(
    const float* __restrict__ x,
    const float* __restrict__ W1,   // (8,128,512) -> expert 0 slice
    const float* __restrict__ B1,   // (8,512)
    const float* __restrict__ Wd,   // (8,3,3,1,512)
    const float* __restrict__ Bd,   // (8,512)
    const float* __restrict__ W2,   // (8,512,128) -> expert 0 slice
    const float* __restrict__ B2,   // (8,128)
    const float* __restrict__ s0,
    const unsigned char* __restrict__ hitpart,
    float* __restrict__ out)
{
    __shared__ float gls[HID];
    __shared__ float red[256];
    __shared__ unsigned int hm[NB];
    __shared__ float gate_s;

    int b = blockIdx.x >> 3;
    int w = blockIdx.x & 7;      // token position = gate index
    int tid = threadIdx.x;

    // OR-reduce hitpart (512 bytes = 32 uint4): 2 uint4 per batch, no atomics
    if (tid < NB) {
        const uint4* hp = (const uint4*)hitpart;
        uint4 v0 = hp[tid * 2], v1 = hp[tid * 2 + 1];
        unsigned int m = v0.x | v0.y | v0.z | v0.w | v1.x | v1.y | v1.z | v1.w;
        m |= m >> 16; m |= m >> 8; m &= 0xffu;
        hm[tid] = m;
    }

    // fc1 for (rows 0..1) x (cols w-1..w+1), channels c=tid and c+256.
    // x addresses are block-uniform -> compiler scalarizes to s_load.
    float acc0[6], acc1[6];      // [row*3+ci]
    #pragma unroll
    for (int p = 0; p < 6; p++) { acc0[p] = 0.f; acc1[p] = 0.f; }

    const float* xb = x + (size_t)b * NTOK * DIM;

    #pragma unroll 2
    for (int d0 = 0; d0 < DIM; d0 += 4) {
        float wa[4], wb[4];
        #pragma unroll
        for (int j = 0; j < 4; j++) {
            wa[j] = W1[(size_t)(d0 + j) * HID + tid];
            wb[j] = W1[(size_t)(d0 + j) * HID + tid + 256];
        }
        #pragma unroll
        for (int row = 0; row < 2; row++) {
            #pragma unroll
            for (int ci = 0; ci < 3; ci++) {
                int col = w - 1 + ci;        // block-uniform branch
                if (col < 0) continue;       // col <= 8 always in-range
                const float* xp = xb + (size_t)(row * 64 + col) * DIM + d0;
                float x0 = xp[0], x1 = xp[1], x2 = xp[2], x3 = xp[3];
                int p = row * 3 + ci;
                acc0[p] += x0 * wa[0] + x1 * wa[1] + x2 * wa[2] + x3 * wa[3];
                acc1[p] += x0 * wb[0] + x1 * wb[1] + x2 * wb[2] + x3 * wb[3];
            }
        }
    }

    // + B1, depthwise 3x3 (kernel rows kh=1,2 hit input rows 0,1), + Bd, gelu
    {
        float b1a = B1[tid], b1b = B1[tid + 256];
        float ya = Bd[tid], yb = Bd[tid + 256];
        #pragma unroll
        for (int ci = 0; ci < 3; ci++) {
            int col = w - 1 + ci;
            if (col < 0) continue;           // padded -> contributes 0
            float w1a = Wd[(size_t)(3 + ci) * HID + tid];
            float w2a = Wd[(size_t)(6 + ci) * HID + tid];
            float w1b = Wd[(size_t)(3 + ci) * HID + tid + 256];
            float w2b = Wd[(size_t)(6 + ci) * HID + tid + 256];
            ya += (acc0[ci] + b1a) * w1a + (acc0[3 + ci] + b1a) * w2a;
            yb += (acc1[ci] + b1b) * w1b + (acc1[3 + ci] + b1b) * w2b;
        }
        gls[tid]       = 0.5f * ya * (1.0f + erff(ya * 0.70710678118654752f));
        gls[tid + 256] = 0.5f * yb * (1.0f + erff(yb * 0.70710678118654752f));
    }
    __syncthreads();   // gls complete + hm complete

    if (tid == 0) {
        float denom = 1e-6f, mine = 0.f;
        for (int bb = 0; bb < NB; bb++) {
            float v = ((hm[bb] >> w) & 1u) ? s0[bb * NE + w] : 0.f;
            denom += v;
            if (bb == b) mine = v;
        }
        gate_s = 16.0f * mine / denom;
    }

    // fc2: 2-way c-split, lane = output channel, 16 W2 loads in flight
    int o    = tid & 127;
    int half = tid >> 7;
    const float* wp = W2 + (size_t)(half * 256) * NOUT + o;
    const float4* gp = (const float4*)&gls[half * 256];
    float a = 0.f;
    for (int cb = 0; cb < 256; cb += 16) {
        float wv[16];
        #pragma unroll
        for (int k = 0; k < 16; k++) wv[k] = wp[(size_t)(cb + k) * NOUT];
        float4 g0 = gp[(cb >> 2) + 0];
        float4 g1 = gp[(cb >> 2) + 1];
        float4 g2 = gp[(cb >> 2) + 2];
        float4 g3 = gp[(cb >> 2) + 3];
        a += g0.x * wv[0]  + g0.y * wv[1]  + g0.z * wv[2]  + g0.w * wv[3]
           + g1.x * wv[4]  + g1.y * wv[5]  + g1.z * wv[6]  + g1.w * wv[7]
           + g2.x * wv[8]  + g2.y * wv[9]  + g2.z * wv[10] + g2.w * wv[11]
           + g3.x * wv[12] + g3.y * wv[13] + g3.z * wv[14] + g3.w * wv[15];
    }
    red[tid] = a;
    __syncthreads();
    if (tid < 128) {
        out[((size_t)b * NTOK + w) * NOUT + o] =
            (red[tid] + red[tid + 128] + B2[o]) * gate_s;
    }
}

extern "C" void kernel_launch(void* const* d_in, const int* in_sizes, int n_in,
                              void* d_out, int out_size, void* d_ws, size_t ws_size,
                              hipStream_t stream) {
    const float* x  = (const float*)d_in[0];
    // d_in[1] = H, d_in[2] = W (ints) — fixed 64x64, hard-coded
    const float* wg = (const float*)d_in[3];
    const float* bg = (const float*)d_in[4];
    const float* W1 = (const float*)d_in[5];
    const float* B1 = (const float*)d_in[6];
    const float* Wd = (const float*)d_in[7];
    const float* Bd = (const float*)d_in[8];
    const float* W2 = (const float*)d_in[9];
    const float* B2 = (const float*)d_in[10];

    float* s0              = (float*)d_ws;
    unsigned char* hitpart = (unsigned char*)d_ws + 512;

    gate_kernel<<<GBLK, 256, 0, stream>>>(
        (const float4*)x, wg, bg, s0, hitpart, (float4*)d_out);
    expert_kernel<<<NB * 8, 256, 0, stream>>>(
        x, W1, B1, Wd, Bd, W2, B2, s0, hitpart, (float*)d_out);
}

// Round 9
// 123.321 us; speedup vs baseline: 1.4899x; 1.0901x over previous
//
#include <hip/hip_runtime.h>
#include <math.h>

#define NB   16      // batch
#define NTOK 4096    // N = 64*64
#define DIM  128
#define NE   8
#define HID  512
#define NOUT 128
#define GBLK 512     // gate blocks: each covers 128 contiguous tokens

// ws layout (all bytes read are written first each call):
//   s0      float[16*8]   @ 0    (512 B)
//   hitpart byte[512]     @ 512  (512 B)

// 8 lanes per token, grid-stride x4 tokens per lane, gate weights hoisted
// into VGPRs once per block. Coalesced float4 x reads, 3-step butterfly,
// per-block hit bitmask, softmax score for expert 0 at n<8, zero-fill of
// output rows issued first (overlaps load latency).
__global__ __launch_bounds__(256) void gate_kernel(
    const float4* __restrict__ x,        // (16,4096,128) f32 as float4
    const float* __restrict__ wg,        // (128,8)
    const float* __restrict__ bg,        // (8)
    float* __restrict__ s0,              // ws (16,8)
    unsigned char* __restrict__ hitpart, // ws (512) one byte per block
    float4* __restrict__ out)            // (16,4096,128) f32
{
    __shared__ float4 lw4[NE][DIM / 4];  // wg transposed
    __shared__ float lbg[NE];
    __shared__ unsigned int lmask;

    int tid = threadIdx.x;
    {   // stage wg transposed (one float4 per thread)
        int e = tid >> 5, s = tid & 31, d0 = s * 4;
        float4 w;
        w.x = wg[(d0 + 0) * NE + e];
        w.y = wg[(d0 + 1) * NE + e];
        w.z = wg[(d0 + 2) * NE + e];
        w.w = wg[(d0 + 3) * NE + e];
        lw4[e][s] = w;
    }
    if (tid < NE) lbg[tid] = bg[tid];
    if (tid == 0) lmask = 0u;
    __syncthreads();

    int sub  = tid & 7;       // lane-within-token
    int tgrp = tid >> 3;      // token-within-chunk (0..31)

    // hoist this lane's weight slice into VGPRs (reused for all 4 groups)
    float4 wv[NE][4];
    #pragma unroll
    for (int e = 0; e < NE; e++)
        #pragma unroll
        for (int k = 0; k < 4; k++) wv[e][k] = lw4[e][sub + 8 * k];

    #pragma unroll 2
    for (int it = 0; it < 4; it++) {
        int tok = (blockIdx.x << 7) + (it << 5) + tgrp;   // 0..65535
        int b   = tok >> 12;
        int n   = tok & 4095;
        size_t base = (size_t)tok * 32 + sub;

        // zero-fill first: independent stores overlap the load latency
        float4 zz = make_float4(0.f, 0.f, 0.f, 0.f);
        out[base]      = zz;
        out[base + 8]  = zz;
        out[base + 16] = zz;
        out[base + 24] = zz;

        float4 xv0 = x[base];
        float4 xv1 = x[base + 8];
        float4 xv2 = x[base + 16];
        float4 xv3 = x[base + 24];

        float z[NE];
        #pragma unroll
        for (int e = 0; e < NE; e++) {
            z[e] = xv0.x * wv[e][0].x + xv0.y * wv[e][0].y
                 + xv0.z * wv[e][0].z + xv0.w * wv[e][0].w
                 + xv1.x * wv[e][1].x + xv1.y * wv[e][1].y
                 + xv1.z * wv[e][1].z + xv1.w * wv[e][1].w
                 + xv2.x * wv[e][2].x + xv2.y * wv[e][2].y
                 + xv2.z * wv[e][2].z + xv2.w * wv[e][2].w
                 + xv3.x * wv[e][3].x + xv3.y * wv[e][3].y
                 + xv3.z * wv[e][3].z + xv3.w * wv[e][3].w;
        }

        // butterfly sum across the 8 lanes of this token (xor 1,2,4)
        #pragma unroll
        for (int off = 1; off <= 4; off <<= 1) {
            #pragma unroll
            for (int e = 0; e < NE; e++) z[e] += __shfl_xor(z[e], off);
        }

        if (sub == 0) {
            float zf[NE];
            #pragma unroll
            for (int e = 0; e < NE; e++) zf[e] = z[e] + lbg[e];

            int am = 0;
            float mz = zf[0];
            #pragma unroll
            for (int e = 1; e < NE; e++) {
                if (zf[e] > mz) { mz = zf[e]; am = e; }
            }
            atomicOr(&lmask, 1u << am);   // LDS atomic

            if (n < 8) {                   // softmax score for expert 0
                float s = 0.f;
                #pragma unroll
                for (int e = 0; e < NE; e++) s += expf(zf[e] - mz);
                s0[b * NE + n] = expf(zf[0] - mz) / s;
            }
        }
    }

    __syncthreads();
    if (tid == 0) hitpart[blockIdx.x] = (unsigned char)lmask;
}

// Fused expert-0 MixFFN + gate scale for the 128 nonzero output rows.
// grid = 16 batches x 8 token positions (w), 256 threads.
// All hot loads are vector loads with deep batching; x rows staged in LDS
// (no in-loop scalar loads). fc1 K-split-2: thread (q = tid&127, kh = tid>>7)
// owns channels 4q..4q+3 over d-range [kh*64, kh*64+64); partials reduced
// via LDS; dwconv in registers; fc2 with 32-wide W2 load batches.
__global__ __launch_bounds__(256) void expert_kernel(
    const float* __restrict__ x,
    const float* __restrict__ W1,   // (8,128,512) -> expert 0 slice
    const float* __restrict__ B1,   // (8,512)
    const float* __restrict__ Wd,   // (8,3,3,1,512)
    const float* __restrict__ Bd,   // (8,512)
    const float* __restrict__ W2,   // (8,512,128) -> expert 0 slice
    const float* __restrict__ B2,   // (8,128)
    const float* __restrict__ s0,
    const unsigned char* __restrict__ hitpart,
    float* __restrict__ out)
{
    __shared__ float4 xs4[6][32];     //  3 KB: xs[p][d], p = row*3 + ci
    __shared__ float4 redb[128][6];   // 12 KB: k-half-1 fc1 partials
    __shared__ float gls[HID];        //  2 KB
    __shared__ float red2[256];
    __shared__ unsigned int hm[NB];
    __shared__ float gate_s;

    int b = blockIdx.x >> 3;
    int w = blockIdx.x & 7;      // token position = gate index
    int tid = threadIdx.x;

    // hit bitmask (512 B = 32 uint4): 2 uint4 per batch, no atomics
    if (tid < NB) {
        const uint4* hp = (const uint4*)hitpart;
        uint4 v0 = hp[tid * 2], v1 = hp[tid * 2 + 1];
        unsigned int m = v0.x | v0.y | v0.z | v0.w | v1.x | v1.y | v1.z | v1.w;
        m |= m >> 16; m |= m >> 8; m &= 0xffu;
        hm[tid] = m;
    }

    // stage x rows (row 0..1) x (cols w-1..w+1): 192 float4, coalesced.
    // col<0 clamps to 0 (garbage values; dwconv skips that tap).
    if (tid < 192) {
        int p = tid >> 5, dq = tid & 31;
        int row = p / 3, ci = p % 3;
        int col = w - 1 + ci;
        if (col < 0) col = 0;
        xs4[p][dq] = ((const float4*)x)[((size_t)b * NTOK + row * 64 + col) * 32 + dq];
    }
    __syncthreads();

    if (tid == 0) {
        float denom = 1e-6f, mine = 0.f;
        for (int bb = 0; bb < NB; bb++) {
            float v = ((hm[bb] >> w) & 1u) ? s0[bb * NE + w] : 0.f;
            denom += v;
            if (bb == b) mine = v;
        }
        gate_s = 16.0f * mine / denom;
    }

    // fc1: acc[p][j] = sum_d xs[p][d] * W1[d][4q+j], K-split over kh
    int q  = tid & 127;       // float4-column: channels 4q..4q+3
    int kh = tid >> 7;        // 0/1: d in [kh*64, kh*64+64)
    float4 acc[6];
    #pragma unroll
    for (int p = 0; p < 6; p++) acc[p] = make_float4(0.f, 0.f, 0.f, 0.f);

    const float4* W14 = (const float4*)W1;   // [128][128] float4 view
    #pragma unroll 4
    for (int s = 0; s < 16; s++) {
        int d0 = kh * 64 + s * 4;
        float4 wv0 = W14[(size_t)(d0 + 0) * 128 + q];
        float4 wv1 = W14[(size_t)(d0 + 1) * 128 + q];
        float4 wv2 = W14[(size_t)(d0 + 2) * 128 + q];
        float4 wv3 = W14[(size_t)(d0 + 3) * 128 + q];
        #pragma unroll
        for (int p = 0; p < 6; p++) {
            float4 xv = xs4[p][kh * 16 + s];
            acc[p].x += xv.x * wv0.x + xv.y * wv1.x + xv.z * wv2.x + xv.w * wv3.x;
            acc[p].y += xv.x * wv0.y + xv.y * wv1.y + xv.z * wv2.y + xv.w * wv3.y;
            acc[p].z += xv.x * wv0.z + xv.y * wv1.z + xv.z * wv2.z + xv.w * wv3.z;
            acc[p].w += xv.x * wv0.w + xv.y * wv1.w + xv.z * wv2.w + xv.w * wv3.w;
        }
    }

    // reduce the two k-halves via LDS
    if (kh == 1) {
        #pragma unroll
        for (int p = 0; p < 6; p++) redb[q][p] = acc[p];
    }
    __syncthreads();

    // dwconv + biases + exact gelu on the low-half threads (4 channels each)
    if (kh == 0) {
        #pragma unroll
        for (int p = 0; p < 6; p++) {
            float4 r = redb[q][p];
            acc[p].x += r.x; acc[p].y += r.y; acc[p].z += r.z; acc[p].w += r.w;
        }
        float4 b1 = ((const float4*)B1)[q];
        float4 y  = ((const float4*)Bd)[q];
        #pragma unroll
        for (int ci = 0; ci < 3; ci++) {
            int col = w - 1 + ci;
            if (col < 0) continue;   // SAME-padding: h1 entry is 0, skip tap
            float4 wda = ((const float4*)Wd)[(3 + ci) * 128 + q];  // kh=1 -> row 0
            float4 wdb = ((const float4*)Wd)[(6 + ci) * 128 + q];  // kh=2 -> row 1
            float4 a0 = acc[ci];       // row 0, this col
            float4 a1 = acc[3 + ci];   // row 1, this col
            y.x += (a0.x + b1.x) * wda.x + (a1.x + b1.x) * wdb.x;
            y.y += (a0.y + b1.y) * wda.y + (a1.y + b1.y) * wdb.y;
            y.z += (a0.z + b1.z) * wda.z + (a1.z + b1.z) * wdb.z;
            y.w += (a0.w + b1.w) * wda.w + (a1.w + b1.w) * wdb.w;
        }
        const float k = 0.70710678118654752f;
        float4 g;
        g.x = 0.5f * y.x * (1.0f + erff(y.x * k));
        g.y = 0.5f * y.y * (1.0f + erff(y.y * k));
        g.z = 0.5f * y.z * (1.0f + erff(y.z * k));
        g.w = 0.5f * y.w * (1.0f + erff(y.w * k));
        ((float4*)gls)[q] = g;
    }
    __syncthreads();

    // fc2: 2-way c-split, lane = output channel, 32 W2 loads in flight
    int o    = tid & 127;
    int half = tid >> 7;
    const float* wp = W2 + (size_t)(half * 256) * NOUT + o;
    const float4* gp = (const float4*)&gls[half * 256];
    float a = 0.f;
    #pragma unroll
    for (int cb = 0; cb < 256; cb += 32) {
        float wv[32];
        #pragma unroll
        for (int k2 = 0; k2 < 32; k2++) wv[k2] = wp[(size_t)(cb + k2) * NOUT];
        #pragma unroll
        for (int k2 = 0; k2 < 32; k2 += 4) {
            float4 g = gp[(cb + k2) >> 2];
            a += g.x * wv[k2] + g.y * wv[k2 + 1] + g.z * wv[k2 + 2] + g.w * wv[k2 + 3];
        }
    }
    red2[tid] = a;
    __syncthreads();
    if (tid < 128) {
        out[((size_t)b * NTOK + w) * NOUT + o] =
            (red2[tid] + red2[tid + 128] + B2[o]) * gate_s;
    }
}

extern "C" void kernel_launch(void* const* d_in, const int* in_sizes, int n_in,
                              void* d_out, int out_size, void* d_ws, size_t ws_size,
                              hipStream_t stream) {
    const float* x  = (const float*)d_in[0];
    // d_in[1] = H, d_in[2] = W (ints) — fixed 64x64, hard-coded
    const float* wg = (const float*)d_in[3];
    const float* bg = (const float*)d_in[4];
    const float* W1 = (const float*)d_in[5];
    const float* B1 = (const float*)d_in[6];
    const float* Wd = (const float*)d_in[7];
    const float* Bd = (const float*)d_in[8];
    const float* W2 = (const float*)d_in[9];
    const float* B2 = (const float*)d_in[10];

    float* s0              = (float*)d_ws;
    unsigned char* hitpart = (unsigned char*)d_ws + 512;

    gate_kernel<<<GBLK, 256, 0, stream>>>(
        (const float4*)x, wg, bg, s0, hitpart, (float4*)d_out);
    expert_kernel<<<NB * 8, 256, 0, stream>>>(
        x, W1, B1, Wd, Bd, W2, B2, s0, hitpart, (float*)d_out);
}